// Round 2
// baseline (466.646 us; speedup 1.0000x reference)
//
#include <hip/hip_runtime.h>
#include <hip/hip_bf16.h>

typedef unsigned short u16;
typedef unsigned int u32;
typedef u16 u16x4 __attribute__((ext_vector_type(4)));
typedef u16 u16x8 __attribute__((ext_vector_type(8)));
typedef short bf16x8 __attribute__((ext_vector_type(8)));
typedef float f32x4 __attribute__((ext_vector_type(4)));

static __device__ __forceinline__ u16 f32_to_bf16(float f) {
    u32 b = __float_as_uint(f);
    u32 r = (b + 0x7fffu + ((b >> 16) & 1u)) >> 16;
    return (u16)r;
}

// ---------- convert x (fp32 -> bf16) ----------
__global__ __launch_bounds__(256) void k_cvt_x(const float* __restrict__ x, u16* __restrict__ xb, int n) {
    int i = (blockIdx.x * 256 + threadIdx.x) * 4;
    if (i < n) {
        const float4 v = *reinterpret_cast<const float4*>(x + i);
        u16x4 o = { f32_to_bf16(v.x), f32_to_bf16(v.y), f32_to_bf16(v.z), f32_to_bf16(v.w) };
        *reinterpret_cast<u16x4*>(xb + i) = o;
    }
}

// ---------- convert + transpose weight: wtb[r][o][i] = W[r][i][o], bf16 ----------
__global__ __launch_bounds__(256) void k_cvt_w(const float* __restrict__ w, u16* __restrict__ wtb, int total) {
    int idx = blockIdx.x * 256 + threadIdx.x;
    if (idx < total) {
        int r = idx >> 14, rem = idx & 16383, o = rem >> 7, i = rem & 127;
        wtb[idx] = f32_to_bf16(w[(r << 14) + (i << 7) + o]);
    }
}

// ---------- histogram of dst ----------
__global__ __launch_bounds__(256) void k_hist(const int* __restrict__ dst, int* __restrict__ counts, int E) {
    int e = blockIdx.x * 256 + threadIdx.x;
    if (e < E) atomicAdd(&counts[dst[e]], 1);
}

// ---------- scan kernel 1: per-block (1024 elems) exclusive scan ----------
__global__ __launch_bounds__(256) void k_scan1(const int* __restrict__ counts, int* __restrict__ offsets,
                                               int* __restrict__ bsum, int n) {
    __shared__ int wsum[4];
    int tid = threadIdx.x;
    int base = blockIdx.x * 1024 + tid * 4;
    int c[4];
#pragma unroll
    for (int j = 0; j < 4; ++j) c[j] = (base + j < n) ? counts[base + j] : 0;
    int t = c[0] + c[1] + c[2] + c[3];
    int lane = tid & 63, wid = tid >> 6;
    int s = t;
#pragma unroll
    for (int off = 1; off < 64; off <<= 1) {
        int v = __shfl_up(s, off, 64);
        if (lane >= off) s += v;
    }
    if (lane == 63) wsum[wid] = s;
    __syncthreads();
    int woff = 0;
    for (int wq = 0; wq < wid; ++wq) woff += wsum[wq];
    int run = woff + s - t;  // exclusive prefix for this thread's first element
#pragma unroll
    for (int j = 0; j < 4; ++j) {
        if (base + j < n) offsets[base + j] = run;
        run += c[j];
    }
    if (tid == 255) bsum[blockIdx.x] = woff + s;  // block total
}

// ---------- scan kernel 2: scan block sums (nb <= 64), write grand total ----------
__global__ void k_scan2(const int* __restrict__ bsum, int* __restrict__ bo, int* __restrict__ offsets,
                        int nb, int n) {
    int lane = threadIdx.x;
    int v = (lane < nb) ? bsum[lane] : 0;
    int s = v;
#pragma unroll
    for (int off = 1; off < 64; off <<= 1) {
        int u = __shfl_up(s, off, 64);
        if (lane >= off) s += u;
    }
    if (lane < nb) bo[lane] = s - v;   // exclusive block offset
    if (lane == 63) offsets[n] = s;    // total edge count
}

// ---------- scan kernel 3: add block offsets ----------
__global__ __launch_bounds__(256) void k_scan3(int* __restrict__ offsets, const int* __restrict__ bo, int n) {
    int i = blockIdx.x * 256 + threadIdx.x;
    if (i < n) offsets[i] += bo[i >> 10];
}

// ---------- fill CSR buckets with packed meta ----------
__global__ __launch_bounds__(256) void k_fill(const int* __restrict__ src, const int* __restrict__ dst,
                                              const int* __restrict__ rel, const float* __restrict__ norm,
                                              const int* __restrict__ offsets, int* __restrict__ cursor,
                                              uint2* __restrict__ meta, int E) {
    int e = blockIdx.x * 256 + threadIdx.x;
    if (e < E) {
        int d = dst[e];
        int pos = offsets[d] + atomicAdd(&cursor[d], 1);
        u32 packed = (u32)src[e] | ((u32)rel[e] << 16);  // src < 65536, rel < 8
        meta[pos] = make_uint2(packed, __float_as_uint(norm[e]));
    }
}

// ---------- bf16 MFMA GEMM: hw[g] = x @ W[c0+g], 128x128 block tile ----------
__global__ __launch_bounds__(256) void k_gemm(const u16* __restrict__ xb, const u16* __restrict__ wtb,
                                              u16* __restrict__ hw, int M) {
    __shared__ u16 As[128 * 128];
    __shared__ u16 Bs[128 * 128];
    const int tid = threadIdx.x;
    const int m0 = blockIdx.x * 128;
    const int g = blockIdx.y;
    const u16* wt = wtb + ((size_t)g << 14);
    // stage A (x rows, XOR-swizzled) and B (W^T rows, same swizzle)
    for (int i = tid; i < 128 * 16; i += 256) {
        int row = i >> 4, ch = i & 15;
        int sw = (ch * 8) ^ ((row & 7) << 3);
        u16x8 av = {0, 0, 0, 0, 0, 0, 0, 0};
        int grow = m0 + row;
        if (grow < M) av = *reinterpret_cast<const u16x8*>(xb + (size_t)grow * 128 + ch * 8);
        *reinterpret_cast<u16x8*>(&As[row * 128 + sw]) = av;
        u16x8 bv = *reinterpret_cast<const u16x8*>(wt + row * 128 + ch * 8);
        *reinterpret_cast<u16x8*>(&Bs[row * 128 + sw]) = bv;
    }
    __syncthreads();
    const int lane = tid & 63, wid = tid >> 6;
    const int wm = wid >> 1, wn = wid & 1;
    const int l16 = lane & 15, kg = lane >> 4;
    f32x4 acc[4][4];
#pragma unroll
    for (int a = 0; a < 4; ++a)
#pragma unroll
        for (int b = 0; b < 4; ++b) acc[a][b] = {0.f, 0.f, 0.f, 0.f};
#pragma unroll
    for (int ks = 0; ks < 4; ++ks) {
        const int kb = ks * 32 + kg * 8;
        bf16x8 af[4], bfr[4];
#pragma unroll
        for (int fi = 0; fi < 4; ++fi) {
            int row = wm * 64 + fi * 16 + l16;
            af[fi] = *reinterpret_cast<const bf16x8*>(&As[row * 128 + (kb ^ ((row & 7) << 3))]);
        }
#pragma unroll
        for (int fj = 0; fj < 4; ++fj) {
            int row = wn * 64 + fj * 16 + l16;
            bfr[fj] = *reinterpret_cast<const bf16x8*>(&Bs[row * 128 + (kb ^ ((row & 7) << 3))]);
        }
#pragma unroll
        for (int fi = 0; fi < 4; ++fi)
#pragma unroll
            for (int fj = 0; fj < 4; ++fj)
                acc[fi][fj] = __builtin_amdgcn_mfma_f32_16x16x32_bf16(af[fi], bfr[fj], acc[fi][fj], 0, 0, 0);
    }
    u16* hwg = hw + (size_t)g * M * 128;
#pragma unroll
    for (int fi = 0; fi < 4; ++fi) {
#pragma unroll
        for (int j = 0; j < 4; ++j) {
            int gr = m0 + wm * 64 + fi * 16 + kg * 4 + j;
            if (gr < M) {
                u16* rowp = hwg + (size_t)gr * 128 + wn * 64 + l16;
#pragma unroll
                for (int fj = 0; fj < 4; ++fj) rowp[fj * 16] = f32_to_bf16(acc[fi][fj][j]);
            }
        }
    }
}

// ---------- per-dst aggregation: one wave per node, register accumulate ----------
template <bool FIRST, bool LAST>
__global__ __launch_bounds__(256) void k_agg(const uint2* __restrict__ meta, const int* __restrict__ offsets,
                                             const u16* __restrict__ hw, const float* __restrict__ bias,
                                             float* __restrict__ out, int c0, int G, int M) {
    int node = blockIdx.x * 4 + (threadIdx.x >> 6);
    if (node >= M) return;
    int lane = threadIdx.x & 63;
    int e = offsets[node], end = offsets[node + 1];
    float a0 = 0.f, a1 = 0.f;
    for (; e < end; ++e) {
        uint2 mt = meta[e];
        int gg = (int)(mt.x >> 16) - c0;
        if ((unsigned)gg >= (unsigned)G) continue;
        int s = (int)(mt.x & 0xffffu);
        float nrm = __uint_as_float(mt.y);
        const u32* row = reinterpret_cast<const u32*>(hw + (((size_t)gg * M + s) << 7));
        u32 u = row[lane];
        a0 = fmaf(nrm, __uint_as_float(u << 16), a0);
        a1 = fmaf(nrm, __uint_as_float(u & 0xffff0000u), a1);
    }
    float2* o2 = reinterpret_cast<float2*>(out + ((size_t)node << 7));
    float2 prev;
    if (FIRST) {
        prev.x = 0.f; prev.y = 0.f;
    } else {
        prev = o2[lane];
    }
    float r0 = prev.x + a0, r1 = prev.y + a1;
    if (LAST) {
        const float2 bb = reinterpret_cast<const float2*>(bias)[lane];
        r0 = fmaxf(r0 + bb.x, 0.f);
        r1 = fmaxf(r1 + bb.y, 0.f);
    }
    o2[lane] = make_float2(r0, r1);
}

extern "C" void kernel_launch(void* const* d_in, const int* in_sizes, int n_in,
                              void* d_out, int out_size, void* d_ws, size_t ws_size,
                              hipStream_t stream) {
    const float* x    = (const float*)d_in[0];
    const float* norm = (const float*)d_in[1];
    const float* w    = (const float*)d_in[2];
    const float* bias = (const float*)d_in[3];
    const int* src    = (const int*)d_in[4];
    const int* dst    = (const int*)d_in[5];
    const int* rel    = (const int*)d_in[6];
    float* out = (float*)d_out;

    const int M = in_sizes[0] / 128;          // 50000 nodes
    const int E = in_sizes[1];                // 1600000 edges
    const int R = in_sizes[2] / (128 * 128);  // 8 relations

    // ---- carve workspace ----
    char* p = (char*)d_ws;
    auto carve = [&p](size_t bytes) -> char* {
        char* r = p;
        p += (bytes + 255) & ~(size_t)255;
        return r;
    };
    u16* xb      = (u16*)carve((size_t)M * 128 * 2);
    u16* wtb     = (u16*)carve((size_t)R * 128 * 128 * 2);
    int* counts  = (int*)carve((size_t)M * 4);
    int* cursor  = (int*)carve((size_t)M * 4);
    int* offsets = (int*)carve((size_t)(M + 1) * 4);
    int* bsum    = (int*)carve(256);
    int* bo      = (int*)carve(256);
    uint2* meta  = (uint2*)carve((size_t)E * 8);
    size_t used = (size_t)(p - (char*)d_ws);
    size_t per_rel = (size_t)M * 128 * 2;  // bf16 hw slab per relation (12.8 MB)
    size_t avail = (ws_size > used) ? (ws_size - used) : 0;
    int G = (int)(avail / per_rel);
    if (G < 1) G = 1;
    if (G > R) G = R;
    u16* hw = (u16*)p;

    // zero counts (+ its alignment pad) and cursor in one memset
    hipMemsetAsync(counts, 0, (size_t)((char*)cursor - (char*)counts) + (size_t)M * 4, stream);

    {
        int n = M * 128;
        k_cvt_x<<<dim3((n / 4 + 255) / 256), 256, 0, stream>>>(x, xb, n);
    }
    {
        int total = R * 128 * 128;
        k_cvt_w<<<dim3((total + 255) / 256), 256, 0, stream>>>(w, wtb, total);
    }
    k_hist<<<dim3((E + 255) / 256), 256, 0, stream>>>(dst, counts, E);
    int nb = (M + 1023) / 1024;  // 49 (<=64 required by k_scan2)
    k_scan1<<<dim3(nb), 256, 0, stream>>>(counts, offsets, bsum, M);
    k_scan2<<<dim3(1), 64, 0, stream>>>(bsum, bo, offsets, nb, M);
    k_scan3<<<dim3((M + 255) / 256), 256, 0, stream>>>(offsets, bo, M);
    k_fill<<<dim3((E + 255) / 256), 256, 0, stream>>>(src, dst, rel, norm, offsets, cursor, meta, E);

    for (int c0 = 0; c0 < R; c0 += G) {
        int g = (R - c0 < G) ? (R - c0) : G;
        k_gemm<<<dim3((M + 127) / 128, g), 256, 0, stream>>>(xb, wtb + ((size_t)c0 << 14), hw, M);
        bool first = (c0 == 0), last = (c0 + g >= R);
        dim3 gr((M + 3) / 4);
        if (first && last)
            k_agg<true, true><<<gr, 256, 0, stream>>>(meta, offsets, hw, bias, out, c0, g, M);
        else if (first)
            k_agg<true, false><<<gr, 256, 0, stream>>>(meta, offsets, hw, bias, out, c0, g, M);
        else if (last)
            k_agg<false, true><<<gr, 256, 0, stream>>>(meta, offsets, hw, bias, out, c0, g, M);
        else
            k_agg<false, false><<<gr, 256, 0, stream>>>(meta, offsets, hw, bias, out, c0, g, M);
    }
}

// Round 3
// 411.605 us; speedup vs baseline: 1.1337x; 1.1337x over previous
//
#include <hip/hip_runtime.h>
#include <hip/hip_bf16.h>

typedef unsigned short u16;
typedef unsigned int u32;
typedef u16 u16x4 __attribute__((ext_vector_type(4)));
typedef u16 u16x8 __attribute__((ext_vector_type(8)));
typedef short bf16x8 __attribute__((ext_vector_type(8)));
typedef float f32x4 __attribute__((ext_vector_type(4)));

static __device__ __forceinline__ u16 f32_to_bf16(float f) {
    u32 b = __float_as_uint(f);
    u32 r = (b + 0x7fffu + ((b >> 16) & 1u)) >> 16;
    return (u16)r;
}

// async global->LDS, 16B per lane; LDS dest must be wave-uniform base (+lane*16 implicit)
static __device__ __forceinline__ void gload_lds16(const void* g, void* l) {
    __builtin_amdgcn_global_load_lds((const __attribute__((address_space(1))) u32*)g,
                                     (__attribute__((address_space(3))) u32*)l, 16, 0, 0);
}

// ---------- convert x (fp32 -> bf16) ----------
__global__ __launch_bounds__(256) void k_cvt_x(const float* __restrict__ x, u16* __restrict__ xb, int n) {
    int i = (blockIdx.x * 256 + threadIdx.x) * 4;
    if (i < n) {
        const float4 v = *reinterpret_cast<const float4*>(x + i);
        u16x4 o = { f32_to_bf16(v.x), f32_to_bf16(v.y), f32_to_bf16(v.z), f32_to_bf16(v.w) };
        *reinterpret_cast<u16x4*>(xb + i) = o;
    }
}

// ---------- convert + transpose weight: wtb[r][o][i] = W[r][i][o], bf16 ----------
__global__ __launch_bounds__(256) void k_cvt_w(const float* __restrict__ w, u16* __restrict__ wtb, int total) {
    int idx = blockIdx.x * 256 + threadIdx.x;
    if (idx < total) {
        int r = idx >> 14, rem = idx & 16383, o = rem >> 7, i = rem & 127;
        wtb[idx] = f32_to_bf16(w[(r << 14) + (i << 7) + o]);
    }
}

// ---------- histogram over (dst, rel) buckets ----------
__global__ __launch_bounds__(256) void k_hist2(const int* __restrict__ dst, const int* __restrict__ rel,
                                               int* __restrict__ counts, int E) {
    int e = blockIdx.x * 256 + threadIdx.x;
    if (e < E) atomicAdd(&counts[dst[e] * 8 + rel[e]], 1);
}

// ---------- scan kernel 1: per-block (8192 elems) exclusive scan ----------
__global__ __launch_bounds__(256) void k_scan1v(const int* __restrict__ counts, int* __restrict__ offsets,
                                                int* __restrict__ bsum, int n) {
    __shared__ int wsum[4];
    int tid = threadIdx.x;
    int base = blockIdx.x * 8192 + tid * 32;  // n is a multiple of 8192 (padded)
    int4 c[8];
    const int4* cp = reinterpret_cast<const int4*>(counts + base);
#pragma unroll
    for (int j = 0; j < 8; ++j) c[j] = cp[j];
    int t = 0;
#pragma unroll
    for (int j = 0; j < 8; ++j) t += c[j].x + c[j].y + c[j].z + c[j].w;
    int lane = tid & 63, wid = tid >> 6;
    int s = t;
#pragma unroll
    for (int off = 1; off < 64; off <<= 1) {
        int v = __shfl_up(s, off, 64);
        if (lane >= off) s += v;
    }
    if (lane == 63) wsum[wid] = s;
    __syncthreads();
    int woff = 0;
    for (int wq = 0; wq < wid; ++wq) woff += wsum[wq];
    int run = woff + s - t;
    int4* op = reinterpret_cast<int4*>(offsets + base);
#pragma unroll
    for (int j = 0; j < 8; ++j) {
        int4 o;
        o.x = run; run += c[j].x;
        o.y = run; run += c[j].y;
        o.z = run; run += c[j].z;
        o.w = run; run += c[j].w;
        op[j] = o;
    }
    if (tid == 255) bsum[blockIdx.x] = woff + s;
}

// ---------- scan kernel 2: scan block sums (nb <= 64), write grand total ----------
__global__ void k_scan2(const int* __restrict__ bsum, int* __restrict__ bo, int* __restrict__ offsets,
                        int nb, int n) {
    int lane = threadIdx.x;
    int v = (lane < nb) ? bsum[lane] : 0;
    int s = v;
#pragma unroll
    for (int off = 1; off < 64; off <<= 1) {
        int u = __shfl_up(s, off, 64);
        if (lane >= off) s += u;
    }
    if (lane < nb) bo[lane] = s - v;
    if (lane == 63) offsets[n] = s;
}

// ---------- scan kernel 3: add block offsets (int4 vectorized) ----------
__global__ __launch_bounds__(256) void k_scan3v(int* __restrict__ offsets, const int* __restrict__ bo, int n4) {
    int i = blockIdx.x * 256 + threadIdx.x;
    if (i < n4) {
        int4 v = reinterpret_cast<int4*>(offsets)[i];
        int b = bo[i >> 11];  // 2048 int4 per 8192-int scan block
        v.x += b; v.y += b; v.z += b; v.w += b;
        reinterpret_cast<int4*>(offsets)[i] = v;
    }
}

// ---------- fill (dst,rel)-bucketed CSR with {src, norm} ----------
__global__ __launch_bounds__(256) void k_fill2(const int* __restrict__ src, const int* __restrict__ dst,
                                               const int* __restrict__ rel, const float* __restrict__ norm,
                                               const int* __restrict__ offsets, int* __restrict__ cursor,
                                               uint2* __restrict__ meta, int E) {
    int e = blockIdx.x * 256 + threadIdx.x;
    if (e < E) {
        int b = dst[e] * 8 + rel[e];
        int pos = offsets[b] + atomicAdd(&cursor[b], 1);
        meta[pos] = make_uint2((u32)src[e], __float_as_uint(norm[e]));
    }
}

// ---------- per-(dst,rel) aggregation in x-space: agg[d][r][i] = sum norm*x[src][i] ----------
__global__ __launch_bounds__(256) void k_aggx(const uint2* __restrict__ meta, const int* __restrict__ offs,
                                              const u16* __restrict__ xb, u16* __restrict__ agg, int M) {
    int node = blockIdx.x * 4 + (threadIdx.x >> 6);
    if (node >= M) return;
    int lane = threadIdx.x & 63;
    const int ob = node * 8;
    u32* dstp = reinterpret_cast<u32*>(agg + ((size_t)node << 10));
#pragma unroll
    for (int r = 0; r < 8; ++r) {
        int e = offs[ob + r], end = offs[ob + r + 1];
        float s0 = 0.f, s1 = 0.f, t0 = 0.f, t1 = 0.f;
        while (e < end) {
            int rem = end - e;  // wave-uniform
            uint2 m0 = meta[e];
            uint2 m1 = (rem > 1) ? meta[e + 1] : make_uint2(m0.x, 0u);
            uint2 m2 = (rem > 2) ? meta[e + 2] : make_uint2(m0.x, 0u);
            uint2 m3 = (rem > 3) ? meta[e + 3] : make_uint2(m0.x, 0u);
            u32 u0 = reinterpret_cast<const u32*>(xb + ((size_t)m0.x << 7))[lane];
            u32 u1 = reinterpret_cast<const u32*>(xb + ((size_t)m1.x << 7))[lane];
            u32 u2 = reinterpret_cast<const u32*>(xb + ((size_t)m2.x << 7))[lane];
            u32 u3 = reinterpret_cast<const u32*>(xb + ((size_t)m3.x << 7))[lane];
            float n0 = __uint_as_float(m0.y), n1 = __uint_as_float(m1.y);
            float n2 = __uint_as_float(m2.y), n3 = __uint_as_float(m3.y);
            s0 = fmaf(n0, __uint_as_float(u0 << 16), s0);
            s1 = fmaf(n0, __uint_as_float(u0 & 0xffff0000u), s1);
            t0 = fmaf(n1, __uint_as_float(u1 << 16), t0);
            t1 = fmaf(n1, __uint_as_float(u1 & 0xffff0000u), t1);
            s0 = fmaf(n2, __uint_as_float(u2 << 16), s0);
            s1 = fmaf(n2, __uint_as_float(u2 & 0xffff0000u), s1);
            t0 = fmaf(n3, __uint_as_float(u3 << 16), t0);
            t1 = fmaf(n3, __uint_as_float(u3 & 0xffff0000u), t1);
            e += 4;
        }
        u32 pk = (u32)f32_to_bf16(s0 + t0) | ((u32)f32_to_bf16(s1 + t1) << 16);
        dstp[r * 64 + lane] = pk;
    }
}

// ---------- fused GEMM: out = relu(agg[M,1024] @ Wcat[1024,128] + bias), K-loop over 8 relations ----------
__global__ __launch_bounds__(256) void k_gemm2(const u16* __restrict__ agg, const u16* __restrict__ wtb,
                                               const float* __restrict__ bias, float* __restrict__ out, int M) {
    __shared__ u16 As[128 * 128];
    __shared__ u16 Bs[128 * 128];
    const int tid = threadIdx.x;
    const int lane = tid & 63, wid = tid >> 6;
    const int m0 = blockIdx.x * 128;
    const int wm = wid >> 1, wn = wid & 1;
    const int l16 = lane & 15, kg = lane >> 4;
    f32x4 acc[4][4];
#pragma unroll
    for (int a = 0; a < 4; ++a)
#pragma unroll
        for (int b = 0; b < 4; ++b) acc[a][b] = {0.f, 0.f, 0.f, 0.f};

#pragma unroll 1
    for (int g = 0; g < 8; ++g) {
        // stage via global_load_lds: LDS linear, source chunk pre-swizzled (involution ch ^= row&7)
#pragma unroll
        for (int it = 0; it < 8; ++it) {
            int cb = (it * 4 + wid) * 64;         // wave-uniform chunk base (16B units)
            int c = cb + lane;                    // this lane's chunk
            int row = c >> 4;
            int ch = (c & 15) ^ (row & 7);
            int grow = m0 + row;
            if (grow >= M) grow = M - 1;          // clamp: rows >= M discarded at C-write
            gload_lds16(agg + (((size_t)grow << 10) + (g << 7) + (ch << 3)), &As[cb * 8]);
            gload_lds16(wtb + ((g << 14) + (row << 7) + (ch << 3)), &Bs[cb * 8]);
        }
        __syncthreads();
#pragma unroll
        for (int ks = 0; ks < 4; ++ks) {
            const int kb = ks * 32 + kg * 8;
            bf16x8 af[4], bfr[4];
#pragma unroll
            for (int fi = 0; fi < 4; ++fi) {
                int row = wm * 64 + fi * 16 + l16;
                af[fi] = *reinterpret_cast<const bf16x8*>(&As[row * 128 + (kb ^ ((row & 7) << 3))]);
            }
#pragma unroll
            for (int fj = 0; fj < 4; ++fj) {
                int row = wn * 64 + fj * 16 + l16;
                bfr[fj] = *reinterpret_cast<const bf16x8*>(&Bs[row * 128 + (kb ^ ((row & 7) << 3))]);
            }
#pragma unroll
            for (int fi = 0; fi < 4; ++fi)
#pragma unroll
                for (int fj = 0; fj < 4; ++fj)
                    acc[fi][fj] = __builtin_amdgcn_mfma_f32_16x16x32_bf16(af[fi], bfr[fj], acc[fi][fj], 0, 0, 0);
        }
        __syncthreads();
    }
    // epilogue: + bias, relu, f32 store
    float bv[4];
#pragma unroll
    for (int fj = 0; fj < 4; ++fj) bv[fj] = bias[wn * 64 + fj * 16 + l16];
#pragma unroll
    for (int fi = 0; fi < 4; ++fi) {
#pragma unroll
        for (int j = 0; j < 4; ++j) {
            int gr = m0 + wm * 64 + fi * 16 + kg * 4 + j;
            if (gr < M) {
                float* rowp = out + (((size_t)gr << 7) + wn * 64 + l16);
#pragma unroll
                for (int fj = 0; fj < 4; ++fj)
                    rowp[fj * 16] = fmaxf(acc[fi][fj][j] + bv[fj], 0.f);
            }
        }
    }
}

extern "C" void kernel_launch(void* const* d_in, const int* in_sizes, int n_in,
                              void* d_out, int out_size, void* d_ws, size_t ws_size,
                              hipStream_t stream) {
    const float* x    = (const float*)d_in[0];
    const float* norm = (const float*)d_in[1];
    const float* w    = (const float*)d_in[2];
    const float* bias = (const float*)d_in[3];
    const int* src    = (const int*)d_in[4];
    const int* dst    = (const int*)d_in[5];
    const int* rel    = (const int*)d_in[6];
    float* out = (float*)d_out;

    const int M = in_sizes[0] / 128;          // 50000 nodes
    const int E = in_sizes[1];                // 1600000 edges
    const int R = 8;                          // fixed by problem (unrolled in k_aggx)
    const int n2 = M * R;                     // 400000 buckets
    const int nb = (n2 + 8191) / 8192;        // 49 scan blocks (<= 64)
    const int n2p = nb * 8192;                // padded bucket count

    // ---- carve workspace (~131.5 MB total) ----
    char* p = (char*)d_ws;
    auto carve = [&p](size_t bytes) -> char* {
        char* r = p;
        p += (bytes + 255) & ~(size_t)255;
        return r;
    };
    u16* xb      = (u16*)carve((size_t)M * 128 * 2);        // 12.8 MB
    u16* wtb     = (u16*)carve((size_t)R * 128 * 128 * 2);  // 0.26 MB
    int* cnt     = (int*)carve((size_t)n2p * 4);            // 1.6 MB (counts, then cursor)
    int* offs    = (int*)carve((size_t)(n2p + 4) * 4);      // 1.6 MB
    int* bsum    = (int*)carve(512);
    int* bo      = (int*)carve(512);
    uint2* meta  = (uint2*)carve((size_t)E * 8);            // 12.8 MB
    u16* agg     = (u16*)carve((size_t)M * 1024 * 2);       // 102.4 MB

    hipMemsetAsync(cnt, 0, (size_t)n2p * 4, stream);
    k_cvt_x<<<dim3((M * 128 / 4 + 255) / 256), 256, 0, stream>>>(x, xb, M * 128);
    k_cvt_w<<<dim3((R * 128 * 128 + 255) / 256), 256, 0, stream>>>(w, wtb, R * 128 * 128);
    k_hist2<<<dim3((E + 255) / 256), 256, 0, stream>>>(dst, rel, cnt, E);
    k_scan1v<<<dim3(nb), 256, 0, stream>>>(cnt, offs, bsum, n2p);
    k_scan2<<<dim3(1), 64, 0, stream>>>(bsum, bo, offs, nb, n2p);
    k_scan3v<<<dim3((n2p / 4 + 255) / 256), 256, 0, stream>>>(offs, bo, n2p / 4);
    hipMemsetAsync(cnt, 0, (size_t)n2p * 4, stream);  // reuse as cursor
    k_fill2<<<dim3((E + 255) / 256), 256, 0, stream>>>(src, dst, rel, norm, offs, cnt, meta, E);
    k_aggx<<<dim3((M + 3) / 4), 256, 0, stream>>>(meta, offs, xb, agg, M);
    k_gemm2<<<dim3((M + 127) / 128), 256, 0, stream>>>(agg, wtb, bias, out, M);
    (void)ws_size; (void)n_in; (void)out_size;
}